// Round 2
// baseline (723.782 us; speedup 1.0000x reference)
//
#include <hip/hip_runtime.h>
#include <hip/hip_bf16.h>
#include <stdint.h>

// DecoderBlock: x + attn(LN1(x)) -> x2; x2 + FFN(LN2(x2))
// B=4, T=2048, HIDDEN=1024, HEADS=16, HEAD=64, DFF=4096
// Round 2: 256x256 8-phase GEMM (drain-0 safe variant) for QKV(merged)+FF1;
//          attention K/V double-buffer + async stage split + setprio.

#define HID 1024
#define NH 16
#define HD 64
#define DFF 4096
#define BATCH 4
#define SEQ 2048
#define NTOK (BATCH*SEQ)   // 8192

typedef unsigned short u16;
typedef __attribute__((ext_vector_type(4))) float f32x4;
typedef __attribute__((ext_vector_type(8))) __bf16 bf16x8;

__device__ __forceinline__ u16 f2bf(float f) {
    unsigned int u = __float_as_uint(f);
    u = (u + 0x7fffu + ((u >> 16) & 1u)) >> 16;   // RNE
    return (u16)u;
}

__device__ __forceinline__ void gload_lds16(const void* g, void* lds) {
    __builtin_amdgcn_global_load_lds(
        (const __attribute__((address_space(1))) unsigned int*)(uintptr_t)g,
        (__attribute__((address_space(3))) unsigned int*)(uintptr_t)lds, 16, 0, 0);
}

// ---------------- LayerNorm: f32 in -> bf16 out ----------------
__global__ __launch_bounds__(256) void ln_kernel(const float* __restrict__ x,
                                                 const float* __restrict__ g,
                                                 const float* __restrict__ be,
                                                 u16* __restrict__ out) {
    __shared__ float red[10];
    const int row = blockIdx.x, tid = threadIdx.x;
    const float4 v = ((const float4*)(x + (size_t)row * HID))[tid];
    float s  = v.x + v.y + v.z + v.w;
    float s2 = v.x*v.x + v.y*v.y + v.z*v.z + v.w*v.w;
    for (int off = 32; off > 0; off >>= 1) {
        s  += __shfl_down(s, off, 64);
        s2 += __shfl_down(s2, off, 64);
    }
    if ((tid & 63) == 0) { red[tid >> 6] = s; red[4 + (tid >> 6)] = s2; }
    __syncthreads();
    if (tid == 0) {
        red[8] = red[0] + red[1] + red[2] + red[3];
        red[9] = red[4] + red[5] + red[6] + red[7];
    }
    __syncthreads();
    const float mu  = red[8] * (1.f / HID);
    const float var = red[9] * (1.f / HID) - mu * mu;
    const float rstd = rsqrtf(var + 1e-5f);
    const float4 g4 = ((const float4*)g)[tid];
    const float4 b4 = ((const float4*)be)[tid];
    ushort4 o;
    o.x = f2bf((v.x - mu) * rstd * g4.x + b4.x);
    o.y = f2bf((v.y - mu) * rstd * g4.y + b4.y);
    o.z = f2bf((v.z - mu) * rstd * g4.z + b4.z);
    o.w = f2bf((v.w - mu) * rstd * g4.w + b4.w);
    ((ushort4*)(out + (size_t)row * HID))[tid] = o;
}

// ---------------- weight transpose+cast: out[c][r] = (bf16)in[r][c], batched ----------------
__global__ __launch_bounds__(256) void transpose_w(const float* __restrict__ in,
                                                   u16* __restrict__ out, int R, int C) {
    __shared__ float t[32][33];
    const int r0 = blockIdx.x * 32, c0 = blockIdx.y * 32;
    const float* inb = in + (size_t)blockIdx.z * R * C;
    u16* outb = out + (size_t)blockIdx.z * R * C;
    const int tid = threadIdx.x;
    const int tr = tid >> 3, tc = (tid & 7) * 4;
    const float4 v = *(const float4*)&inb[(size_t)(r0 + tr) * C + c0 + tc];
    t[tr][tc] = v.x; t[tr][tc + 1] = v.y; t[tr][tc + 2] = v.z; t[tr][tc + 3] = v.w;
    __syncthreads();
    ushort4 o;
    o.x = f2bf(t[tc + 0][tr]);
    o.y = f2bf(t[tc + 1][tr]);
    o.z = f2bf(t[tc + 2][tr]);
    o.w = f2bf(t[tc + 3][tr]);
    *(ushort4*)&outb[(size_t)(c0 + tr) * R + r0 + tc] = o;
}

// ---------------- V transpose (bf16): [bh][T][64] -> [bh][64][T] ----------------
__global__ __launch_bounds__(256) void transpose_v(const u16* __restrict__ in,
                                                   u16* __restrict__ out) {
    __shared__ u16 t[64][65];
    const int s0 = blockIdx.x * 64;
    const size_t bh = blockIdx.y;
    const u16* inb = in + bh * SEQ * HD;
    u16* outb = out + bh * HD * SEQ;
    const int tid = threadIdx.x;
    const int r = tid >> 2, c = (tid & 3) * 16;
    bf16x8 a = *(const bf16x8*)&inb[(size_t)(s0 + r) * HD + c];
    bf16x8 b = *(const bf16x8*)&inb[(size_t)(s0 + r) * HD + c + 8];
    #pragma unroll
    for (int i = 0; i < 8; i++) {
        t[r][c + i]     = ((const u16*)&a)[i];
        t[r][c + 8 + i] = ((const u16*)&b)[i];
    }
    __syncthreads();
    u16 o0[8], o1[8];
    #pragma unroll
    for (int i = 0; i < 8; i++) { o0[i] = t[c + i][r]; o1[i] = t[c + 8 + i][r]; }
    *(bf16x8*)&outb[(size_t)r * SEQ + s0 + c]     = *(const bf16x8*)o0;
    *(bf16x8*)&outb[(size_t)r * SEQ + s0 + c + 8] = *(const bf16x8*)o1;
}

// ---------------- old 128x128 GEMM (kept for N=1024 sites: Wo, FF2) ----------------
// MODE 1: f32 residual -> outf[r*N+c] = resid[r*N+c] + acc + bias[c]
template <int MODE>
__global__ __launch_bounds__(256) void gemm_kernel(const u16* __restrict__ A,
                                                   const u16* __restrict__ B,
                                                   float* __restrict__ outf,
                                                   u16* __restrict__ outh,
                                                   const float* __restrict__ bias,
                                                   const float* __restrict__ resid,
                                                   int K, int N, float scale) {
    __shared__ u16 Al[128][32];
    __shared__ u16 Bl[128][32];
    const int tid = threadIdx.x;
    const int w = tid >> 6, l = tid & 63;
    const int wr = w >> 1, wc = w & 1;
    const int m0 = blockIdx.x * 128, n0 = blockIdx.y * 128;

    f32x4 acc[4][4] = {};

    const u16* Ag = A + (size_t)(m0 + w * 32) * K;
    const u16* Bg = B + (size_t)(n0 + w * 32) * K;
    const int lr = l >> 2;
    const int lc = (l & 3) * 8;

    for (int k0 = 0; k0 < K; k0 += 32) {
        __syncthreads();
        #pragma unroll
        for (int it = 0; it < 2; it++) {
            gload_lds16(Ag + (size_t)(it * 16 + lr) * K + k0 + lc, &Al[w * 32 + it * 16][0]);
            gload_lds16(Bg + (size_t)(it * 16 + lr) * K + k0 + lc, &Bl[w * 32 + it * 16][0]);
        }
        __syncthreads();
        bf16x8 af[4], bfr[4];
        #pragma unroll
        for (int i = 0; i < 4; i++)
            af[i] = *(const bf16x8*)&Al[wr * 64 + i * 16 + (l & 15)][(l >> 4) * 8];
        #pragma unroll
        for (int i = 0; i < 4; i++)
            bfr[i] = *(const bf16x8*)&Bl[wc * 64 + i * 16 + (l & 15)][(l >> 4) * 8];
        #pragma unroll
        for (int mi = 0; mi < 4; mi++)
            #pragma unroll
            for (int nj = 0; nj < 4; nj++)
                acc[mi][nj] = __builtin_amdgcn_mfma_f32_16x16x32_bf16(af[mi], bfr[nj], acc[mi][nj], 0, 0, 0);
    }

    const int r00 = m0 + wr * 64 + ((l >> 4) << 2);
    const int c00 = n0 + wc * 64 + (l & 15);
    if (MODE == 1) {
        #pragma unroll
        for (int nj = 0; nj < 4; nj++) {
            const int c = c00 + nj * 16;
            const float bi = bias[c];
            #pragma unroll
            for (int mi = 0; mi < 4; mi++)
                #pragma unroll
                for (int j = 0; j < 4; j++) {
                    const int r = r00 + mi * 16 + j;
                    const size_t idx = (size_t)r * N + c;
                    outf[idx] = resid[idx] + acc[mi][nj][j] + bi;
                }
        }
    } else {
        #pragma unroll
        for (int nj = 0; nj < 4; nj++) {
            const int c = c00 + nj * 16;
            const float bi = bias[c];
            #pragma unroll
            for (int mi = 0; mi < 4; mi++)
                #pragma unroll
                for (int j = 0; j < 4; j++) {
                    const int r = r00 + mi * 16 + j;
                    const float v = acc[mi][nj][j] + bi;
                    outh[(size_t)r * N + c] = f2bf(v > 0.f ? v : 0.f);
                }
        }
    }
}

// ---------------- 256x256 8-phase GEMM (drain-0 variant) ----------------
// BM=BN=256, BK=64, 512 thr = 8 waves (2M x 4N), per-wave out 128x64 (acc[8][4]).
// LDS 128KB: buf b at b*65536; A at +0 (256 rows x 128B), B at +32768.
// st_16x32 swizzle: byte colB ^= ((row>>2)&1)<<5 (applied to reads AND pre-applied
// to the global source of global_load_lds so LDS ends up swizzled — rule 21).
// Per tile: 4 phases {12 ds_read_b128; stage 1 half of tile t+1; barrier;
// lgkmcnt(0); setprio(1); 16 MFMA; setprio(0); [q==3: vmcnt(0)]; barrier}.
// Drain-0 at tile boundary is REQUIRED for soundness with 2-tile LDS (each wave
// must cover its own staging contributions to every half before the rendezvous).
// MODE 0: merged QKV scatter (which=c>>10; Q scaled 0.125)
// MODE 2: ReLU bf16
template <int MODE>
__global__ __launch_bounds__(512, 2) void gemm256(const u16* __restrict__ A,
                                                  const u16* __restrict__ B,
                                                  float* __restrict__ outf,
                                                  u16* __restrict__ outh,
                                                  const float* __restrict__ bias,
                                                  const float* __restrict__ resid,
                                                  int K, int N, int nbn) {
    __shared__ char lds[131072];
    const int tid = threadIdx.x;
    const int w = tid >> 6, l = tid & 63;
    const int wr = w >> 2, wc = w & 3;
    const int l15 = l & 15, lg = l >> 4;

    // XCD-bijective block swizzle (m204)
    const int nwg = gridDim.x;
    int wg;
    {
        const int q = nwg >> 3, r = nwg & 7;
        const int xcd = blockIdx.x & 7, lid = blockIdx.x >> 3;
        wg = (xcd < r ? xcd * (q + 1) : r * (q + 1) + (xcd - r) * q) + lid;
    }
    const int nbm = nwg / nbn;
    const int m0 = (wg % nbm) * 256;
    const int n0 = (wg / nbm) * 256;

    const size_t Kb = (size_t)K * 2;
    const int NT = K >> 6;

    f32x4 acc[8][4] = {};

    // stage one 128-row half of A or B (16KB) into buf nxt; q selects operand/half
    auto stage_half = [&](int q, int nxt, int k0) {
        const char* G = (const char*)((q & 2) ? B : A);
        const int row0 = ((q & 2) ? n0 : m0) + (q & 1) * 128;
        char* halfBase = lds + nxt * 65536 + (q & 2) * 16384 + (q & 1) * 16384;
        const int w64 = w << 6;
        #pragma unroll
        for (int it = 0; it < 2; ++it) {
            const int d = (it * 512 + tid) * 16;
            const int cb = (d & 127) ^ (((d >> 9) & 1) << 5);
            const char* g = G + (size_t)(row0 + (d >> 7)) * Kb + (size_t)k0 * 2 + cb;
            gload_lds16(g, halfBase + it * 8192 + w64 * 16);
        }
    };

    // prologue: tile 0 -> buf0, full drain
    #pragma unroll
    for (int q = 0; q < 4; ++q) stage_half(q, 0, 0);
    asm volatile("s_waitcnt vmcnt(0)" ::: "memory");
    __builtin_amdgcn_s_barrier();

    for (int t = 0; t < NT; ++t) {
        const int cur = t & 1;
        const char* lbA = lds + cur * 65536;
        const char* lbB = lbA + 32768;
        const bool pf = (t + 1 < NT);
        #pragma unroll
        for (int q = 0; q < 4; ++q) {
            const int mh = q >> 1, nh = q & 1;
            bf16x8 af[4][2], bfr[2][2];
            #pragma unroll
            for (int mi = 0; mi < 4; ++mi)
                #pragma unroll
                for (int ks = 0; ks < 2; ++ks) {
                    const int row = wr * 128 + (mh * 4 + mi) * 16 + l15;
                    const int cb = ks * 64 + lg * 16;
                    af[mi][ks] = *(const bf16x8*)(lbA + row * 128 + (cb ^ (((row >> 2) & 1) << 5)));
                }
            #pragma unroll
            for (int nj = 0; nj < 2; ++nj)
                #pragma unroll
                for (int ks = 0; ks < 2; ++ks) {
                    const int row = wc * 64 + (nh * 2 + nj) * 16 + l15;
                    const int cb = ks * 64 + lg * 16;
                    bfr[nj][ks] = *(const bf16x8*)(lbB + row * 128 + (cb ^ (((row >> 2) & 1) << 5)));
                }
            if (pf) stage_half(q, cur ^ 1, (t + 1) << 6);
            __builtin_amdgcn_s_barrier();
            asm volatile("s_waitcnt lgkmcnt(0)" ::: "memory");
            __builtin_amdgcn_sched_barrier(0);
            __builtin_amdgcn_s_setprio(1);
            #pragma unroll
            for (int mi = 0; mi < 4; ++mi)
                #pragma unroll
                for (int nj = 0; nj < 2; ++nj)
                    #pragma unroll
                    for (int ks = 0; ks < 2; ++ks)
                        acc[mh * 4 + mi][nh * 2 + nj] = __builtin_amdgcn_mfma_f32_16x16x32_bf16(
                            af[mi][ks], bfr[nj][ks], acc[mh * 4 + mi][nh * 2 + nj], 0, 0, 0);
            __builtin_amdgcn_s_setprio(0);
            if (q == 3 && pf) asm volatile("s_waitcnt vmcnt(0)" ::: "memory");
            __builtin_amdgcn_s_barrier();
        }
    }

    // epilogue
    #pragma unroll
    for (int nj = 0; nj < 4; ++nj) {
        const int c = n0 + wc * 64 + nj * 16 + l15;
        if (MODE == 0) {
            const int which = c >> 10, hc = c & 1023;
            const int h = hc >> 6, d = hc & 63;
            const float scale = (which == 0) ? 0.125f : 1.0f;
            u16* outp = outh + (size_t)which * ((size_t)NTOK * HID);
            #pragma unroll
            for (int mi = 0; mi < 8; ++mi)
                #pragma unroll
                for (int j = 0; j < 4; ++j) {
                    const int r = m0 + wr * 128 + mi * 16 + (lg << 2) + j;
                    const int b = r >> 11, tt = r & (SEQ - 1);
                    outp[((size_t)(b * NH + h) * SEQ + tt) * HD + d] = f2bf(acc[mi][nj][j] * scale);
                }
        } else if (MODE == 1) {
            const float bi = bias[c];
            #pragma unroll
            for (int mi = 0; mi < 8; ++mi)
                #pragma unroll
                for (int j = 0; j < 4; ++j) {
                    const int r = m0 + wr * 128 + mi * 16 + (lg << 2) + j;
                    const size_t idx = (size_t)r * N + c;
                    outf[idx] = resid[idx] + acc[mi][nj][j] + bi;
                }
        } else {
            const float bi = bias[c];
            #pragma unroll
            for (int mi = 0; mi < 8; ++mi)
                #pragma unroll
                for (int j = 0; j < 4; ++j) {
                    const int r = m0 + wr * 128 + mi * 16 + (lg << 2) + j;
                    const float v = acc[mi][nj][j] + bi;
                    outh[(size_t)r * N + c] = f2bf(v > 0.f ? v : 0.f);
                }
        }
    }
}

// ---------------- Flash attention (causal), K/V double-buffered ----------------
// grid (T/64, B*NH); 256 thr = 4 waves; wave w owns Q rows [qt*64+w*16, +16).
// One barrier per tile: after loop-top __syncthreads(), all waves have finished
// reading buf[cur^1] (their iter st-1 reads complete before their MFMAs), so the
// end-of-body ds_write of the prefetched regs into buf[cur^1] is race-free.
__global__ __launch_bounds__(256) void attn_kernel(const u16* __restrict__ Q,
                                                   const u16* __restrict__ K,
                                                   const u16* __restrict__ Vt,
                                                   u16* __restrict__ O) {
    __shared__ u16 Kl[2][64 * 64];
    __shared__ u16 Vl[2][64 * 64];
    __shared__ u16 Pl[4][16 * 64];
    const int qt = blockIdx.x, bh = blockIdx.y;
    const int tid = threadIdx.x, w = tid >> 6, l = tid & 63;
    const int g = l >> 4, c16 = l & 15;

    const u16* Qg = Q + ((size_t)bh * SEQ + qt * 64 + w * 16) * HD;
    bf16x8 qf[2];
    qf[0] = *(const bf16x8*)&Qg[(size_t)c16 * HD + g * 8];
    qf[1] = *(const bf16x8*)&Qg[(size_t)c16 * HD + 32 + g * 8];

    f32x4 o[4] = {};
    float mrow[4], lrow[4];
    #pragma unroll
    for (int j = 0; j < 4; j++) { mrow[j] = -1e30f; lrow[j] = 0.f; }

    const u16* Kg0 = K + (size_t)bh * SEQ * HD;
    const u16* Vg0 = Vt + (size_t)bh * HD * SEQ;
    const int sr = tid >> 2;                 // staging row (0..63), 4 thr/row
    const int scb = (tid & 3) * 32;          // staging col byte (two 16B chunks)
    char* PlB = (char*)&Pl[w][0];

    bf16x8 kreg[2], vreg[2];
    auto load_tile = [&](int st) {
        const char* Kg = (const char*)(Kg0 + (size_t)st * 64 * HD);
        const char* Vg = (const char*)(Vg0 + st * 64);
        #pragma unroll
        for (int it = 0; it < 2; it++) {
            kreg[it] = *(const bf16x8*)(Kg + (size_t)sr * 128 + scb + it * 16);
            vreg[it] = *(const bf16x8*)(Vg + (size_t)sr * (SEQ * 2) + scb + it * 16);
        }
    };
    auto write_tile = [&](int buf) {
        char* KlB = (char*)Kl[buf];
        char* VlB = (char*)Vl[buf];
        const int sw = (sr & 7) << 4;
        #pragma unroll
        for (int it = 0; it < 2; it++) {
            *(bf16x8*)(KlB + sr * 128 + ((scb + it * 16) ^ sw)) = kreg[it];
            *(bf16x8*)(VlB + sr * 128 + ((scb + it * 16) ^ sw)) = vreg[it];
        }
    };

    load_tile(0);
    write_tile(0);

    for (int st = 0; st <= qt; ++st) {
        const int cur = st & 1;
        __syncthreads();                    // buf[cur] visible; buf[cur^1] free
        const bool pf = (st + 1 <= qt);
        if (pf) load_tile(st + 1);          // global -> regs, overlaps compute
        const char* KlB = (const char*)Kl[cur];
        const char* VlB = (const char*)Vl[cur];

        // S = Q K^T
        f32x4 s[4];
        __builtin_amdgcn_s_setprio(1);
        #pragma unroll
        for (int n = 0; n < 4; n++) {
            const int row = n * 16 + c16;
            const char* base = KlB + row * 128;
            bf16x8 b0 = *(const bf16x8*)(base + ((g * 16) ^ ((row & 7) << 4)));
            bf16x8 b1 = *(const bf16x8*)(base + ((64 + g * 16) ^ ((row & 7) << 4)));
            f32x4 z = {};
            z = __builtin_amdgcn_mfma_f32_16x16x32_bf16(qf[0], b0, z, 0, 0, 0);
            s[n] = __builtin_amdgcn_mfma_f32_16x16x32_bf16(qf[1], b1, z, 0, 0, 0);
        }
        __builtin_amdgcn_s_setprio(0);
        if (st == qt) {
            #pragma unroll
            for (int n = 0; n < 4; n++)
                #pragma unroll
                for (int j = 0; j < 4; j++) {
                    const int ql = w * 16 + g * 4 + j, sl = n * 16 + c16;
                    if (sl > ql) s[n][j] = -1e30f;
                }
        }
        // online softmax
        #pragma unroll
        for (int j = 0; j < 4; j++) {
            float mx = fmaxf(fmaxf(s[0][j], s[1][j]), fmaxf(s[2][j], s[3][j]));
            for (int off = 1; off < 16; off <<= 1) mx = fmaxf(mx, __shfl_xor(mx, off, 64));
            const float newm = fmaxf(mrow[j], mx);
            const float sc = __expf(mrow[j] - newm);
            mrow[j] = newm;
            float ps = 0.f;
            #pragma unroll
            for (int n = 0; n < 4; n++) {
                const float p = __expf(s[n][j] - newm);
                s[n][j] = p; ps += p;
            }
            for (int off = 1; off < 16; off <<= 1) ps += __shfl_xor(ps, off, 64);
            lrow[j] = lrow[j] * sc + ps;
            #pragma unroll
            for (int n = 0; n < 4; n++) o[n][j] *= sc;
        }
        // P -> per-wave LDS (bf16, swizzled) -> PV A-operand
        #pragma unroll
        for (int n = 0; n < 4; n++)
            #pragma unroll
            for (int j = 0; j < 4; j++) {
                const int row = g * 4 + j;
                const int cb = (n * 16 + c16) * 2;
                *(u16*)(PlB + row * 128 + (cb ^ ((row & 7) << 4))) = f2bf(s[n][j]);
            }
        bf16x8 pa[2];
        #pragma unroll
        for (int kb = 0; kb < 2; kb++)
            pa[kb] = *(const bf16x8*)(PlB + c16 * 128 + ((kb * 64 + g * 16) ^ ((c16 & 7) << 4)));
        __builtin_amdgcn_s_setprio(1);
        #pragma unroll
        for (int n = 0; n < 4; n++) {
            const int row = n * 16 + c16;
            const char* base = VlB + row * 128;
            bf16x8 v0 = *(const bf16x8*)(base + ((g * 16) ^ ((row & 7) << 4)));
            bf16x8 v1 = *(const bf16x8*)(base + ((64 + g * 16) ^ ((row & 7) << 4)));
            o[n] = __builtin_amdgcn_mfma_f32_16x16x32_bf16(pa[0], v0, o[n], 0, 0, 0);
            o[n] = __builtin_amdgcn_mfma_f32_16x16x32_bf16(pa[1], v1, o[n], 0, 0, 0);
        }
        __builtin_amdgcn_s_setprio(0);
        if (pf) write_tile(cur ^ 1);        // regs -> LDS for next iter
    }

    const int b = bh >> 4, h = bh & 15;
    #pragma unroll
    for (int j = 0; j < 4; j++) {
        const float inv = 1.f / lrow[j];
        const int t = qt * 64 + w * 16 + g * 4 + j;
        #pragma unroll
        for (int n = 0; n < 4; n++)
            O[((size_t)b * SEQ + t) * HID + h * HD + n * 16 + c16] = f2bf(o[n][j] * inv);
    }
}

// ---------------- launch ----------------
extern "C" void kernel_launch(void* const* d_in, const int* in_sizes, int n_in,
                              void* d_out, int out_size, void* d_ws, size_t ws_size,
                              hipStream_t stream) {
    (void)in_sizes; (void)n_in; (void)out_size; (void)ws_size;
    const float* x   = (const float*)d_in[0];
    const float* Wq  = (const float*)d_in[1];
    const float* Wk  = (const float*)d_in[2];
    const float* Wv  = (const float*)d_in[3];
    const float* Wo  = (const float*)d_in[4];
    const float* bo  = (const float*)d_in[5];
    const float* W1  = (const float*)d_in[6];
    const float* b1  = (const float*)d_in[7];
    const float* W2  = (const float*)d_in[8];
    const float* b2  = (const float*)d_in[9];
    const float* g1  = (const float*)d_in[10];
    const float* be1 = (const float*)d_in[11];
    const float* g2  = (const float*)d_in[12];
    const float* be2 = (const float*)d_in[13];
    float* out = (float*)d_out;

    char* ws = (char*)d_ws;
    size_t off = 0;
    auto alloc = [&](size_t bytes) { void* p = ws + off; off += bytes; return p; };
    u16* Wqkv_t = (u16*)alloc((size_t)3 * HID * HID * 2);  // Wq_t|Wk_t|Wv_t contiguous
    u16* Wo_t = (u16*)alloc((size_t)HID * HID * 2);
    u16* W1_t = (u16*)alloc((size_t)DFF * HID * 2);
    u16* W2_t = (u16*)alloc((size_t)HID * DFF * 2);
    u16* h1   = (u16*)alloc((size_t)NTOK * HID * 2);   // reused as h2
    u16* Qb   = (u16*)alloc((size_t)NTOK * HID * 2);
    u16* Kb   = (u16*)alloc((size_t)NTOK * HID * 2);
    u16* Vb   = (u16*)alloc((size_t)NTOK * HID * 2);   // reused as attn_out
    u16* Vt   = (u16*)alloc((size_t)NTOK * HID * 2);
    float* x2 = (float*)alloc((size_t)NTOK * HID * 4);
    u16* ff1  = Qb;   // reuses Q/K/V/Vt region (64MB) after attention+Wo done
    (void)Kb; (void)Vt;

    // weights -> bf16 B^T (QKV into one contiguous 3072xK matrix)
    transpose_w<<<dim3(32, 2, 16), 256, 0, stream>>>(Wq, Wqkv_t, HID, HD);
    transpose_w<<<dim3(32, 2, 16), 256, 0, stream>>>(Wk, Wqkv_t + (size_t)HID * HID, HID, HD);
    transpose_w<<<dim3(32, 2, 16), 256, 0, stream>>>(Wv, Wqkv_t + (size_t)2 * HID * HID, HID, HD);
    transpose_w<<<dim3(32, 32, 1), 256, 0, stream>>>(Wo, Wo_t, HID, HID);
    transpose_w<<<dim3(32, 128, 1), 256, 0, stream>>>(W1, W1_t, HID, DFF);
    transpose_w<<<dim3(128, 32, 1), 256, 0, stream>>>(W2, W2_t, DFF, HID);

    // LN1
    ln_kernel<<<NTOK, 256, 0, stream>>>(x, g1, be1, h1);

    // merged QKV projection: [8192 x 3072] (Q pre-scaled in epilogue)
    gemm256<0><<<dim3((NTOK / 256) * (3072 / 256)), 512, 0, stream>>>(
        h1, Wqkv_t, nullptr, Qb, nullptr, nullptr, HID, 3072, 3072 / 256);

    // V -> V^T per head
    transpose_v<<<dim3(SEQ / 64, BATCH * NH), 256, 0, stream>>>(Vb, Vt);

    // flash attention
    u16* attn_out = Vb;
    attn_kernel<<<dim3(SEQ / 64, BATCH * NH), 256, 0, stream>>>(Qb, Kb, Vt, attn_out);

    // x2 = x + attn_out @ Wo + bo   (N=1024 -> old 128^2 kernel, 512 blocks)
    gemm_kernel<1><<<dim3(64, 8), 256, 0, stream>>>(attn_out, Wo_t, x2, nullptr, bo, x, HID, HID, 1.f);

    // LN2
    ln_kernel<<<NTOK, 256, 0, stream>>>(x2, g2, be2, h1);

    // ff1 = relu(h2 @ W1 + b1)  [8192 x 4096]
    gemm256<2><<<dim3((NTOK / 256) * (DFF / 256)), 512, 0, stream>>>(
        h1, W1_t, nullptr, ff1, b1, nullptr, HID, DFF, DFF / 256);

    // out = x2 + ff1 @ W2 + b2   (N=1024, K=4096 -> old kernel)
    gemm_kernel<1><<<dim3(64, 8), 256, 0, stream>>>(ff1, W2_t, out, nullptr, b2, x2, DFF, HID, 1.f);
}

// Round 3
// 583.730 us; speedup vs baseline: 1.2399x; 1.2399x over previous
//
#include <hip/hip_runtime.h>
#include <hip/hip_bf16.h>
#include <stdint.h>

// DecoderBlock: x + attn(LN1(x)) -> x2; x2 + FFN(LN2(x2))
// B=4, T=2048, HIDDEN=1024, HEADS=16, HEAD=64, DFF=4096
// Round 3: attention rewritten to swapped-QK^T 32x32 MFMA + in-register softmax
//          (cvt_pk + permlane32_swap, defer-max); all GEMMs on proven 128^2 m97
//          structure (QKV merged into one N=3072 launch).

#define HID 1024
#define NH 16
#define HD 64
#define DFF 4096
#define BATCH 4
#define SEQ 2048
#define NTOK (BATCH*SEQ)   // 8192

typedef unsigned short u16;
typedef unsigned int u32;
typedef __attribute__((ext_vector_type(4))) float f32x4;
typedef __attribute__((ext_vector_type(16))) float f32x16;
typedef __attribute__((ext_vector_type(8))) __bf16 bf16x8;

__device__ __forceinline__ u16 f2bf(float f) {
    unsigned int u = __float_as_uint(f);
    u = (u + 0x7fffu + ((u >> 16) & 1u)) >> 16;   // RNE
    return (u16)u;
}

__device__ __forceinline__ u32 cvtpk(float lo, float hi) {
    u32 d;
    asm("v_cvt_pk_bf16_f32 %0, %1, %2" : "=v"(d) : "v"(lo), "v"(hi));
    return d;
}

// a' = {a[0..31], b[0..31]}; b' = {a[32..63], b[32..63]}
__device__ __forceinline__ void plswap(u32& a, u32& b) {
    asm volatile("v_permlane32_swap_b32 %0, %1" : "+v"(a), "+v"(b));
}

__device__ __forceinline__ void gload_lds16(const void* g, void* lds) {
    __builtin_amdgcn_global_load_lds(
        (const __attribute__((address_space(1))) unsigned int*)(uintptr_t)g,
        (__attribute__((address_space(3))) unsigned int*)(uintptr_t)lds, 16, 0, 0);
}

// ---------------- LayerNorm: f32 in -> bf16 out ----------------
__global__ __launch_bounds__(256) void ln_kernel(const float* __restrict__ x,
                                                 const float* __restrict__ g,
                                                 const float* __restrict__ be,
                                                 u16* __restrict__ out) {
    __shared__ float red[10];
    const int row = blockIdx.x, tid = threadIdx.x;
    const float4 v = ((const float4*)(x + (size_t)row * HID))[tid];
    float s  = v.x + v.y + v.z + v.w;
    float s2 = v.x*v.x + v.y*v.y + v.z*v.z + v.w*v.w;
    for (int off = 32; off > 0; off >>= 1) {
        s  += __shfl_down(s, off, 64);
        s2 += __shfl_down(s2, off, 64);
    }
    if ((tid & 63) == 0) { red[tid >> 6] = s; red[4 + (tid >> 6)] = s2; }
    __syncthreads();
    if (tid == 0) {
        red[8] = red[0] + red[1] + red[2] + red[3];
        red[9] = red[4] + red[5] + red[6] + red[7];
    }
    __syncthreads();
    const float mu  = red[8] * (1.f / HID);
    const float var = red[9] * (1.f / HID) - mu * mu;
    const float rstd = rsqrtf(var + 1e-5f);
    const float4 g4 = ((const float4*)g)[tid];
    const float4 b4 = ((const float4*)be)[tid];
    ushort4 o;
    o.x = f2bf((v.x - mu) * rstd * g4.x + b4.x);
    o.y = f2bf((v.y - mu) * rstd * g4.y + b4.y);
    o.z = f2bf((v.z - mu) * rstd * g4.z + b4.z);
    o.w = f2bf((v.w - mu) * rstd * g4.w + b4.w);
    ((ushort4*)(out + (size_t)row * HID))[tid] = o;
}

// ---------------- weight transpose+cast: out[c][r] = (bf16)in[r][c], batched ----------------
__global__ __launch_bounds__(256) void transpose_w(const float* __restrict__ in,
                                                   u16* __restrict__ out, int R, int C) {
    __shared__ float t[32][33];
    const int r0 = blockIdx.x * 32, c0 = blockIdx.y * 32;
    const float* inb = in + (size_t)blockIdx.z * R * C;
    u16* outb = out + (size_t)blockIdx.z * R * C;
    const int tid = threadIdx.x;
    const int tr = tid >> 3, tc = (tid & 7) * 4;
    const float4 v = *(const float4*)&inb[(size_t)(r0 + tr) * C + c0 + tc];
    t[tr][tc] = v.x; t[tr][tc + 1] = v.y; t[tr][tc + 2] = v.z; t[tr][tc + 3] = v.w;
    __syncthreads();
    ushort4 o;
    o.x = f2bf(t[tc + 0][tr]);
    o.y = f2bf(t[tc + 1][tr]);
    o.z = f2bf(t[tc + 2][tr]);
    o.w = f2bf(t[tc + 3][tr]);
    *(ushort4*)&outb[(size_t)(c0 + tr) * R + r0 + tc] = o;
}

// ---------------- V transpose (bf16): [bh][T][64] -> [bh][64][T] ----------------
__global__ __launch_bounds__(256) void transpose_v(const u16* __restrict__ in,
                                                   u16* __restrict__ out) {
    __shared__ u16 t[64][65];
    const int s0 = blockIdx.x * 64;
    const size_t bh = blockIdx.y;
    const u16* inb = in + bh * SEQ * HD;
    u16* outb = out + bh * HD * SEQ;
    const int tid = threadIdx.x;
    const int r = tid >> 2, c = (tid & 3) * 16;
    bf16x8 a = *(const bf16x8*)&inb[(size_t)(s0 + r) * HD + c];
    bf16x8 b = *(const bf16x8*)&inb[(size_t)(s0 + r) * HD + c + 8];
    #pragma unroll
    for (int i = 0; i < 8; i++) {
        t[r][c + i]     = ((const u16*)&a)[i];
        t[r][c + 8 + i] = ((const u16*)&b)[i];
    }
    __syncthreads();
    u16 o0[8], o1[8];
    #pragma unroll
    for (int i = 0; i < 8; i++) { o0[i] = t[c + i][r]; o1[i] = t[c + 8 + i][r]; }
    *(bf16x8*)&outb[(size_t)r * SEQ + s0 + c]     = *(const bf16x8*)o0;
    *(bf16x8*)&outb[(size_t)r * SEQ + s0 + c + 8] = *(const bf16x8*)o1;
}

// ---------------- GEMM: C[M][N] = A[M][K](bf16,rm) * B^T[N][K](bf16,rm), 128^2 m97 ----------------
// MODE 0: merged QKV scatter (which=c>>10; Q scaled 0.125)
// MODE 1: f32 residual -> outf = resid + acc + bias
// MODE 2: ReLU bf16    -> outh = bf16(max(acc+bias,0))
template <int MODE>
__global__ __launch_bounds__(256) void gemm_kernel(const u16* __restrict__ A,
                                                   const u16* __restrict__ B,
                                                   float* __restrict__ outf,
                                                   u16* __restrict__ outh,
                                                   const float* __restrict__ bias,
                                                   const float* __restrict__ resid,
                                                   int K, int N) {
    __shared__ u16 Al[128][32];
    __shared__ u16 Bl[128][32];
    const int tid = threadIdx.x;
    const int w = tid >> 6, l = tid & 63;
    const int wr = w >> 1, wc = w & 1;
    const int m0 = blockIdx.x * 128, n0 = blockIdx.y * 128;

    f32x4 acc[4][4] = {};

    const u16* Ag = A + (size_t)(m0 + w * 32) * K;
    const u16* Bg = B + (size_t)(n0 + w * 32) * K;
    const int lr = l >> 2;
    const int lc = (l & 3) * 8;

    for (int k0 = 0; k0 < K; k0 += 32) {
        __syncthreads();
        #pragma unroll
        for (int it = 0; it < 2; it++) {
            gload_lds16(Ag + (size_t)(it * 16 + lr) * K + k0 + lc, &Al[w * 32 + it * 16][0]);
            gload_lds16(Bg + (size_t)(it * 16 + lr) * K + k0 + lc, &Bl[w * 32 + it * 16][0]);
        }
        __syncthreads();
        bf16x8 af[4], bfr[4];
        #pragma unroll
        for (int i = 0; i < 4; i++)
            af[i] = *(const bf16x8*)&Al[wr * 64 + i * 16 + (l & 15)][(l >> 4) * 8];
        #pragma unroll
        for (int i = 0; i < 4; i++)
            bfr[i] = *(const bf16x8*)&Bl[wc * 64 + i * 16 + (l & 15)][(l >> 4) * 8];
        #pragma unroll
        for (int mi = 0; mi < 4; mi++)
            #pragma unroll
            for (int nj = 0; nj < 4; nj++)
                acc[mi][nj] = __builtin_amdgcn_mfma_f32_16x16x32_bf16(af[mi], bfr[nj], acc[mi][nj], 0, 0, 0);
    }

    const int r00 = m0 + wr * 64 + ((l >> 4) << 2);
    const int c00 = n0 + wc * 64 + (l & 15);
    if (MODE == 0) {
        #pragma unroll
        for (int nj = 0; nj < 4; nj++) {
            const int c = c00 + nj * 16;
            const int which = c >> 10, hc = c & 1023;
            const int h = hc >> 6, d = hc & 63;
            const float sc2 = (which == 0) ? 0.125f : 1.0f;
            u16* outp = outh + (size_t)which * ((size_t)NTOK * HID);
            #pragma unroll
            for (int mi = 0; mi < 4; mi++)
                #pragma unroll
                for (int j = 0; j < 4; j++) {
                    const int r = r00 + mi * 16 + j;
                    const int b = r >> 11, t = r & (SEQ - 1);
                    outp[((size_t)(b * NH + h) * SEQ + t) * HD + d] = f2bf(acc[mi][nj][j] * sc2);
                }
        }
    } else if (MODE == 1) {
        #pragma unroll
        for (int nj = 0; nj < 4; nj++) {
            const int c = c00 + nj * 16;
            const float bi = bias[c];
            #pragma unroll
            for (int mi = 0; mi < 4; mi++)
                #pragma unroll
                for (int j = 0; j < 4; j++) {
                    const int r = r00 + mi * 16 + j;
                    const size_t idx = (size_t)r * N + c;
                    outf[idx] = resid[idx] + acc[mi][nj][j] + bi;
                }
        }
    } else {
        #pragma unroll
        for (int nj = 0; nj < 4; nj++) {
            const int c = c00 + nj * 16;
            const float bi = bias[c];
            #pragma unroll
            for (int mi = 0; mi < 4; mi++)
                #pragma unroll
                for (int j = 0; j < 4; j++) {
                    const int r = r00 + mi * 16 + j;
                    const float v = acc[mi][nj][j] + bi;
                    outh[(size_t)r * N + c] = f2bf(v > 0.f ? v : 0.f);
                }
        }
    }
}

// ---------------- Flash attention (causal), swapped-QK^T 32x32, in-reg softmax ----------------
// grid (T/128, B*NH); 256 thr = 4 waves; wave w owns 32 q-rows [qt*128+w*32, +32).
// Lane owns q = qbase + (lane&31); lane and lane^32 split the kv-row between them.
// QK^T: S^T = mfma32(A=K_frag, B=Q_frag)  -> lane holds S[q][kv] for 32 kv values.
// Softmax fully in-lane (+1 shfl_xor(32) combine). P packed via cvt_pk_bf16 +
// permlane32_swap directly into PV B-fragments (no LDS P). PV: O^T = mfma32(Vt, P).
// K/V tiles 64x64 bf16 in LDS (XOR swizzle (row&7)<<4), double-buffered with
// async global->reg prefetch overlapped with compute.
__global__ __launch_bounds__(256) void attn_kernel(const u16* __restrict__ Q,
                                                   const u16* __restrict__ K,
                                                   const u16* __restrict__ Vt,
                                                   u16* __restrict__ O) {
    __shared__ u16 Kl[2][64 * 64];
    __shared__ u16 Vl[2][64 * 64];
    const int qt = (gridDim.x - 1) - blockIdx.x;   // heavy blocks first
    const int bh = blockIdx.y;
    const int tid = threadIdx.x, w = tid >> 6, l = tid & 63;
    const int q32 = l & 31, hi = l >> 5;
    const int qbase = qt * 128 + w * 32;
    const int qrow = qbase + q32;

    // Q fragments (B-operand): qf[c] = Q[qrow][c*16 + hi*8 .. +7]
    const u16* Qg = Q + ((size_t)bh * SEQ + qrow) * HD;
    bf16x8 qf[4];
    #pragma unroll
    for (int c = 0; c < 4; ++c)
        qf[c] = *(const bf16x8*)&Qg[c * 16 + hi * 8];

    f32x16 oa[2] = {};        // O^T acc: oa[dblk][r] = O[qrow][dblk*32 + crow(r,hi)]
    float m = -1e30f, lsum = 0.f;

    const u16* Kg0 = K + (size_t)bh * SEQ * HD;
    const u16* Vg0 = Vt + (size_t)bh * HD * SEQ;
    const int sr = tid >> 2;                 // staging row (0..63)
    const int scb = (tid & 3) * 32;          // staging col byte

    bf16x8 kreg[2], vreg[2];
    auto load_tile = [&](int st) {
        const char* Kg = (const char*)(Kg0 + (size_t)st * 64 * HD);
        const char* Vg = (const char*)(Vg0 + st * 64);
        #pragma unroll
        for (int it = 0; it < 2; it++) {
            kreg[it] = *(const bf16x8*)(Kg + (size_t)sr * 128 + scb + it * 16);
            vreg[it] = *(const bf16x8*)(Vg + (size_t)sr * (SEQ * 2) + scb + it * 16);
        }
    };
    auto write_tile = [&](int buf) {
        char* KlB = (char*)Kl[buf];
        char* VlB = (char*)Vl[buf];
        const int sw = (sr & 7) << 4;
        #pragma unroll
        for (int it = 0; it < 2; it++) {
            *(bf16x8*)(KlB + sr * 128 + ((scb + it * 16) ^ sw)) = kreg[it];
            *(bf16x8*)(VlB + sr * 128 + ((scb + it * 16) ^ sw)) = vreg[it];
        }
    };

    const int ntiles = 2 * qt + 2;
    const int tlast = (qbase + 31) >> 6;     // this warp's diagonal tile

    load_tile(0);
    write_tile(0);

    for (int st = 0; st < ntiles; ++st) {
        const int cur = st & 1;
        __syncthreads();                     // buf[cur] ready; buf[cur^1] free
        const bool pf = (st + 1 < ntiles);
        if (pf) load_tile(st + 1);           // global -> regs, overlaps compute

        if (st <= tlast) {
            const char* KlB = (const char*)Kl[cur];
            const char* VlB = (const char*)Vl[cur];

            // ---- S^T = K_tile . Q^T : s[a][r] = S[qrow][st*64 + a*32 + crow(r,hi)]
            f32x16 s[2];
            __builtin_amdgcn_s_setprio(1);
            #pragma unroll
            for (int a = 0; a < 2; ++a) {
                const int row = a * 32 + q32;
                const char* base = KlB + row * 128;
                const int sw = (row & 7) << 4;
                f32x16 accs = {};
                #pragma unroll
                for (int ds4 = 0; ds4 < 4; ++ds4) {
                    bf16x8 kf = *(const bf16x8*)(base + ((ds4 * 32 + hi * 16) ^ sw));
                    accs = __builtin_amdgcn_mfma_f32_32x32x16_bf16(kf, qf[ds4], accs, 0, 0, 0);
                }
                s[a] = accs;
            }
            __builtin_amdgcn_s_setprio(0);

            // ---- causal mask (diagonal tile only)
            if (st == tlast) {
                const int st64 = st * 64;
                #pragma unroll
                for (int a = 0; a < 2; ++a)
                    #pragma unroll
                    for (int r = 0; r < 16; ++r) {
                        const int kvg = st64 + a * 32 + (r & 3) + 8 * (r >> 2) + 4 * hi;
                        if (kvg > qrow) s[a][r] = -1e30f;
                    }
            }

            // ---- in-lane max (+ partner combine)
            float pm0 = -1e30f, pm1 = -1e30f, pm2 = -1e30f, pm3 = -1e30f;
            #pragma unroll
            for (int r = 0; r < 16; r += 4) {
                pm0 = fmaxf(pm0, fmaxf(s[0][r + 0], s[1][r + 0]));
                pm1 = fmaxf(pm1, fmaxf(s[0][r + 1], s[1][r + 1]));
                pm2 = fmaxf(pm2, fmaxf(s[0][r + 2], s[1][r + 2]));
                pm3 = fmaxf(pm3, fmaxf(s[0][r + 3], s[1][r + 3]));
            }
            float pmax = fmaxf(fmaxf(pm0, pm1), fmaxf(pm2, pm3));
            pmax = fmaxf(pmax, __shfl_xor(pmax, 32, 64));

            // ---- defer-max rescale (T13, THR=8)
            if (!__all(pmax <= m + 8.f)) {
                const float newm = fmaxf(m, pmax);
                const float sc = __expf(m - newm);
                m = newm;
                lsum *= sc;
                #pragma unroll
                for (int d = 0; d < 2; ++d)
                    #pragma unroll
                    for (int r = 0; r < 16; ++r)
                        oa[d][r] *= sc;
            }

            // ---- p = exp(s - m), row-sum
            float s0 = 0.f, s1 = 0.f, s2 = 0.f, s3 = 0.f;
            #pragma unroll
            for (int a = 0; a < 2; ++a)
                #pragma unroll
                for (int r = 0; r < 16; r += 4) {
                    float p0 = __expf(s[a][r + 0] - m);
                    float p1 = __expf(s[a][r + 1] - m);
                    float p2 = __expf(s[a][r + 2] - m);
                    float p3 = __expf(s[a][r + 3] - m);
                    s[a][r + 0] = p0; s[a][r + 1] = p1;
                    s[a][r + 2] = p2; s[a][r + 3] = p3;
                    s0 += p0; s1 += p1; s2 += p2; s3 += p3;
                }
            float psum = (s0 + s1) + (s2 + s3);
            psum += __shfl_xor(psum, 32, 64);
            lsum += psum;

            // ---- pack P -> PV B-fragments: pa[s4] = P[qrow][s4*16 + hi*8 .. +7]
            u32 W[2][4][2];
            #pragma unroll
            for (int a = 0; a < 2; ++a)
                #pragma unroll
                for (int i = 0; i < 4; ++i) {
                    W[a][i][0] = cvtpk(s[a][4 * i + 0], s[a][4 * i + 1]);
                    W[a][i][1] = cvtpk(s[a][4 * i + 2], s[a][4 * i + 3]);
                }
            bf16x8 pa[4];
            #pragma unroll
            for (int a = 0; a < 2; ++a)
                #pragma unroll
                for (int j = 0; j < 2; ++j) {
                    u32 a0 = W[a][2 * j][0], b0 = W[a][2 * j + 1][0];
                    u32 a1 = W[a][2 * j][1], b1 = W[a][2 * j + 1][1];
                    plswap(a0, b0);
                    plswap(a1, b1);
                    union { u32 ww[4]; bf16x8 v; } u_;
                    u_.ww[0] = a0; u_.ww[1] = a1; u_.ww[2] = b0; u_.ww[3] = b1;
                    pa[2 * a + j] = u_.v;
                }

            // ---- O^T += Vt_tile . P : oa[dblk] over 4 kv-steps
            __builtin_amdgcn_s_setprio(1);
            #pragma unroll
            for (int dblk = 0; dblk < 2; ++dblk) {
                const int row = dblk * 32 + q32;
                const char* base = VlB + row * 128;
                const int sw = (row & 7) << 4;
                #pragma unroll
                for (int s4 = 0; s4 < 4; ++s4) {
                    bf16x8 vf = *(const bf16x8*)(base + ((s4 * 32 + hi * 16) ^ sw));
                    oa[dblk] = __builtin_amdgcn_mfma_f32_32x32x16_bf16(vf, pa[s4], oa[dblk], 0, 0, 0);
                }
            }
            __builtin_amdgcn_s_setprio(0);
        }

        if (pf) write_tile(cur ^ 1);         // regs -> LDS for next iter
    }

    // ---- epilogue: O[qrow][d] = oa/lsum, concat-head layout [b][t][h*64+d]
    const int b = bh >> 4, h = bh & 15;
    const float inv = 1.f / lsum;
    u16* Orow = O + ((size_t)b * SEQ + qrow) * HID + h * HD;
    #pragma unroll
    for (int dblk = 0; dblk < 2; ++dblk)
        #pragma unroll
        for (int i = 0; i < 4; ++i) {
            ushort4 st4;
            st4.x = f2bf(oa[dblk][4 * i + 0] * inv);
            st4.y = f2bf(oa[dblk][4 * i + 1] * inv);
            st4.z = f2bf(oa[dblk][4 * i + 2] * inv);
            st4.w = f2bf(oa[dblk][4 * i + 3] * inv);
            *(ushort4*)&Orow[dblk * 32 + 8 * i + 4 * hi] = st4;
        }
}

// ---------------- launch ----------------
extern "C" void kernel_launch(void* const* d_in, const int* in_sizes, int n_in,
                              void* d_out, int out_size, void* d_ws, size_t ws_size,
                              hipStream_t stream) {
    (void)in_sizes; (void)n_in; (void)out_size; (void)ws_size;
    const float* x   = (const float*)d_in[0];
    const float* Wq  = (const float*)d_in[1];
    const float* Wk  = (const float*)d_in[2];
    const float* Wv  = (const float*)d_in[3];
    const float* Wo  = (const float*)d_in[4];
    const float* bo  = (const float*)d_in[5];
    const float* W1  = (const float*)d_in[6];
    const float* b1  = (const float*)d_in[7];
    const float* W2  = (const float*)d_in[8];
    const float* b2  = (const float*)d_in[9];
    const float* g1  = (const float*)d_in[10];
    const float* be1 = (const float*)d_in[11];
    const float* g2  = (const float*)d_in[12];
    const float* be2 = (const float*)d_in[13];
    float* out = (float*)d_out;

    char* ws = (char*)d_ws;
    size_t off = 0;
    auto alloc = [&](size_t bytes) { void* p = ws + off; off += bytes; return p; };
    u16* Wqkv_t = (u16*)alloc((size_t)3 * HID * HID * 2);  // Wq_t|Wk_t|Wv_t contiguous
    u16* Wo_t = (u16*)alloc((size_t)HID * HID * 2);
    u16* W1_t = (u16*)alloc((size_t)DFF * HID * 2);
    u16* W2_t = (u16*)alloc((size_t)HID * DFF * 2);
    u16* h1   = (u16*)alloc((size_t)NTOK * HID * 2);   // reused as h2
    u16* Qb   = (u16*)alloc((size_t)NTOK * HID * 2);
    u16* Kb   = (u16*)alloc((size_t)NTOK * HID * 2);
    u16* Vb   = (u16*)alloc((size_t)NTOK * HID * 2);   // reused as attn_out
    u16* Vt   = (u16*)alloc((size_t)NTOK * HID * 2);
    float* x2 = (float*)alloc((size_t)NTOK * HID * 4);
    u16* ff1  = Qb;   // reuses Q region after attention+Wo done

    // weights -> bf16 B^T (QKV contiguous -> one 3072xK B matrix)
    transpose_w<<<dim3(32, 2, 16), 256, 0, stream>>>(Wq, Wqkv_t, HID, HD);
    transpose_w<<<dim3(32, 2, 16), 256, 0, stream>>>(Wk, Wqkv_t + (size_t)HID * HID, HID, HD);
    transpose_w<<<dim3(32, 2, 16), 256, 0, stream>>>(Wv, Wqkv_t + (size_t)2 * HID * HID, HID, HD);
    transpose_w<<<dim3(32, 32, 1), 256, 0, stream>>>(Wo, Wo_t, HID, HID);
    transpose_w<<<dim3(32, 128, 1), 256, 0, stream>>>(W1, W1_t, HID, DFF);
    transpose_w<<<dim3(128, 32, 1), 256, 0, stream>>>(W2, W2_t, DFF, HID);

    // LN1
    ln_kernel<<<NTOK, 256, 0, stream>>>(x, g1, be1, h1);

    // merged QKV projection: [8192 x 3072] (Q pre-scaled 0.125 in epilogue)
    gemm_kernel<0><<<dim3(64, 24), 256, 0, stream>>>(h1, Wqkv_t, nullptr, Qb,
                                                     nullptr, nullptr, HID, 3072);

    // V -> V^T per head
    transpose_v<<<dim3(SEQ / 64, BATCH * NH), 256, 0, stream>>>(Vb, Vt);

    // flash attention (QBLK=128)
    u16* attn_out = Vb;
    attn_kernel<<<dim3(SEQ / 128, BATCH * NH), 256, 0, stream>>>(Qb, Kb, Vt, attn_out);

    // x2 = x + attn_out @ Wo + bo
    gemm_kernel<1><<<dim3(64, 8), 256, 0, stream>>>(attn_out, Wo_t, x2, nullptr, bo, x, HID, HID);

    // LN2
    ln_kernel<<<NTOK, 256, 0, stream>>>(x2, g2, be2, h1);

    // ff1 = relu(h2 @ W1 + b1)  [8192 x 4096]
    gemm_kernel<2><<<dim3(64, 32), 256, 0, stream>>>(h1, W1_t, nullptr, ff1, b1, nullptr, HID, DFF);

    // out = x2 + ff1 @ W2 + b2  [8192 x 1024], K=4096
    gemm_kernel<1><<<dim3(64, 8), 256, 0, stream>>>(ff1, W2_t, out, nullptr, b2, x2, DFF, HID);
}

// Round 5
// 561.181 us; speedup vs baseline: 1.2897x; 1.0402x over previous
//
#include <hip/hip_runtime.h>
#include <hip/hip_bf16.h>
#include <stdint.h>

// DecoderBlock: x + attn(LN1(x)) -> x2; x2 + FFN(LN2(x2))
// B=4, T=2048, HIDDEN=1024, HEADS=16, HEAD=64, DFF=4096
// Round 5 (= round 4 resubmit; acquisition timed out, kernel never ran):
// GEMMs on a counted-vmcnt software pipeline (ring of 4 K-half slices, never
// drains; T3+T4+T5), conflict-free LDS via pre-swizzled global source;
// attention staging write-conflict fix.

#define HID 1024
#define NH 16
#define HD 64
#define DFF 4096
#define BATCH 4
#define SEQ 2048
#define NTOK (BATCH*SEQ)   // 8192

typedef unsigned short u16;
typedef unsigned int u32;
typedef __attribute__((ext_vector_type(4))) float f32x4;
typedef __attribute__((ext_vector_type(16))) float f32x16;
typedef __attribute__((ext_vector_type(8))) __bf16 bf16x8;

__device__ __forceinline__ u16 f2bf(float f) {
    unsigned int u = __float_as_uint(f);
    u = (u + 0x7fffu + ((u >> 16) & 1u)) >> 16;   // RNE
    return (u16)u;
}

__device__ __forceinline__ u32 cvtpk(float lo, float hi) {
    u32 d;
    asm("v_cvt_pk_bf16_f32 %0, %1, %2" : "=v"(d) : "v"(lo), "v"(hi));
    return d;
}

__device__ __forceinline__ void plswap(u32& a, u32& b) {
    asm volatile("v_permlane32_swap_b32 %0, %1" : "+v"(a), "+v"(b));
}

__device__ __forceinline__ void gload_lds16(const void* g, void* lds) {
    __builtin_amdgcn_global_load_lds(
        (const __attribute__((address_space(1))) unsigned int*)(uintptr_t)g,
        (__attribute__((address_space(3))) unsigned int*)(uintptr_t)lds, 16, 0, 0);
}

template <int N>
__device__ __forceinline__ void waitvm() {
    if constexpr (N == 8)      asm volatile("s_waitcnt vmcnt(8)" ::: "memory");
    else if constexpr (N == 6) asm volatile("s_waitcnt vmcnt(6)" ::: "memory");
    else if constexpr (N == 4) asm volatile("s_waitcnt vmcnt(4)" ::: "memory");
    else if constexpr (N == 3) asm volatile("s_waitcnt vmcnt(3)" ::: "memory");
    else                       asm volatile("s_waitcnt vmcnt(0)" ::: "memory");
}

__device__ __forceinline__ void pipe_barrier() {
    __builtin_amdgcn_sched_barrier(0);
    __builtin_amdgcn_s_barrier();
    __builtin_amdgcn_sched_barrier(0);
}

// ---------------- LayerNorm: f32 in -> bf16 out ----------------
__global__ __launch_bounds__(256) void ln_kernel(const float* __restrict__ x,
                                                 const float* __restrict__ g,
                                                 const float* __restrict__ be,
                                                 u16* __restrict__ out) {
    __shared__ float red[10];
    const int row = blockIdx.x, tid = threadIdx.x;
    const float4 v = ((const float4*)(x + (size_t)row * HID))[tid];
    float s  = v.x + v.y + v.z + v.w;
    float s2 = v.x*v.x + v.y*v.y + v.z*v.z + v.w*v.w;
    for (int off = 32; off > 0; off >>= 1) {
        s  += __shfl_down(s, off, 64);
        s2 += __shfl_down(s2, off, 64);
    }
    if ((tid & 63) == 0) { red[tid >> 6] = s; red[4 + (tid >> 6)] = s2; }
    __syncthreads();
    if (tid == 0) {
        red[8] = red[0] + red[1] + red[2] + red[3];
        red[9] = red[4] + red[5] + red[6] + red[7];
    }
    __syncthreads();
    const float mu  = red[8] * (1.f / HID);
    const float var = red[9] * (1.f / HID) - mu * mu;
    const float rstd = rsqrtf(var + 1e-5f);
    const float4 g4 = ((const float4*)g)[tid];
    const float4 b4 = ((const float4*)be)[tid];
    ushort4 o;
    o.x = f2bf((v.x - mu) * rstd * g4.x + b4.x);
    o.y = f2bf((v.y - mu) * rstd * g4.y + b4.y);
    o.z = f2bf((v.z - mu) * rstd * g4.z + b4.z);
    o.w = f2bf((v.w - mu) * rstd * g4.w + b4.w);
    ((ushort4*)(out + (size_t)row * HID))[tid] = o;
}

// ---------------- weight transpose+cast: out[c][r] = (bf16)in[r][c], batched ----------------
__global__ __launch_bounds__(256) void transpose_w(const float* __restrict__ in,
                                                   u16* __restrict__ out, int R, int C) {
    __shared__ float t[32][33];
    const int r0 = blockIdx.x * 32, c0 = blockIdx.y * 32;
    const float* inb = in + (size_t)blockIdx.z * R * C;
    u16* outb = out + (size_t)blockIdx.z * R * C;
    const int tid = threadIdx.x;
    const int tr = tid >> 3, tc = (tid & 7) * 4;
    const float4 v = *(const float4*)&inb[(size_t)(r0 + tr) * C + c0 + tc];
    t[tr][tc] = v.x; t[tr][tc + 1] = v.y; t[tr][tc + 2] = v.z; t[tr][tc + 3] = v.w;
    __syncthreads();
    ushort4 o;
    o.x = f2bf(t[tc + 0][tr]);
    o.y = f2bf(t[tc + 1][tr]);
    o.z = f2bf(t[tc + 2][tr]);
    o.w = f2bf(t[tc + 3][tr]);
    *(ushort4*)&outb[(size_t)(c0 + tr) * R + r0 + tc] = o;
}

// ---------------- V transpose (bf16): [bh][T][64] -> [bh][64][T] ----------------
__global__ __launch_bounds__(256) void transpose_v(const u16* __restrict__ in,
                                                   u16* __restrict__ out) {
    __shared__ u16 t[64][65];
    const int s0 = blockIdx.x * 64;
    const size_t bh = blockIdx.y;
    const u16* inb = in + bh * SEQ * HD;
    u16* outb = out + bh * HD * SEQ;
    const int tid = threadIdx.x;
    const int r = tid >> 2, c = (tid & 3) * 16;
    bf16x8 a = *(const bf16x8*)&inb[(size_t)(s0 + r) * HD + c];
    bf16x8 b = *(const bf16x8*)&inb[(size_t)(s0 + r) * HD + c + 8];
    #pragma unroll
    for (int i = 0; i < 8; i++) {
        t[r][c + i]     = ((const u16*)&a)[i];
        t[r][c + 8 + i] = ((const u16*)&b)[i];
    }
    __syncthreads();
    u16 o0[8], o1[8];
    #pragma unroll
    for (int i = 0; i < 8; i++) { o0[i] = t[c + i][r]; o1[i] = t[c + 8 + i][r]; }
    *(bf16x8*)&outb[(size_t)r * SEQ + s0 + c]     = *(const bf16x8*)o0;
    *(bf16x8*)&outb[(size_t)r * SEQ + s0 + c + 8] = *(const bf16x8*)o1;
}

// ---------------- pipelined GEMM: C[M][N] = A[M][K](bf16,rm) * B^T[N][K](bf16,rm) ----------------
// BM=256, BN template {256,128}. 512 thr = 8 waves; BN=256: 2Mx4N waves (out 128x64,
// acc[8][4]); BN=128: 4Mx2N (out 64x64, acc[4][4]). K split into 32-wide half-steps;
// ring of 4 LDS slices per operand. Iter h: compute slot h&3; stage h+3 into slot
// (h+3)&3 (overwrites h-1, retired before previous barrier); vmcnt(2*LPS) retires
// h+1's own loads; s_barrier globalizes. 3 half-tiles permanently in flight (T3+T4).
// LDS slice layout: 128B line L = rows (L, L+LINES) paired, XOR-swizzled
// ((l15&7)<<4) -> ds_read_b128 2-way (free). Staged via pre-swizzled global source
// (rule 21: gload_lds dest stays linear).
// MODE 0: QKV scatter (N=3072; which=c>>10, Q scaled 0.125). MODE 1: f32 resid+bias.
// MODE 2: ReLU bf16.
template <int BN, int MODE>
__global__ __launch_bounds__(512, 2) void gemm_p(const u16* __restrict__ A,
                                                 const u16* __restrict__ B,
                                                 float* __restrict__ outf,
                                                 u16* __restrict__ outh,
                                                 const float* __restrict__ bias,
                                                 const float* __restrict__ resid,
                                                 int K, int N) {
    constexpr int ASL = 16384;                    // A slice: 256 rows x 32 K x 2B
    constexpr int BSL = (BN == 256) ? 16384 : 8192;
    constexpr int BRD = (BN == 256) ? 2 : 1;      // B staging rounds (A always 2)
    constexpr int LPS = 2 + BRD;                  // loads per stage per thread
    constexpr int WN  = (BN == 256) ? 4 : 2;
    constexpr int MR  = (BN == 256) ? 128 : 64;   // rows per wave
    constexpr int MF  = MR / 16;
    __shared__ char lds[4 * ASL + 4 * BSL];
    char* const ldsB = lds + 4 * ASL;

    const int tid = threadIdx.x;
    const int w = tid >> 6, l = tid & 63;
    const int l15 = l & 15, lg = l >> 4;
    const int wr = w / WN, wc = w % WN;
    const int m0 = (blockIdx.x & 31) * 256;       // M = 8192 always
    const int n0 = (blockIdx.x >> 5) * BN;
    const size_t Kb = (size_t)K * 2;
    const int H = K >> 5;

    // staging source precompute: invert the swizzled LDS layout at linear pos p
    int gar[2], gac[2], gbr[BRD], gbc[BRD];
    #pragma unroll
    for (int rd = 0; rd < 2; ++rd) {
        const int p = rd * 8192 + tid * 16;
        const int line = p >> 7, s16 = (p >> 4) & 7;
        const int u = (s16 * 16) ^ ((line & 7) << 4);
        gar[rd] = line + ((u >> 6) & 1) * 128;
        gac[rd] = u & 63;
    }
    #pragma unroll
    for (int rd = 0; rd < BRD; ++rd) {
        const int p = rd * 8192 + tid * 16;
        const int line = p >> 7, s16 = (p >> 4) & 7;
        const int u = (s16 * 16) ^ ((line & 7) << 4);
        gbr[rd] = line + ((u >> 6) & 1) * ((BN == 256) ? 128 : 64);
        gbc[rd] = u & 63;
    }

    const char* Ag = (const char*)A + (size_t)m0 * Kb;
    const char* Bg = (const char*)B + (size_t)n0 * Kb;

    auto stage = [&](int h) {
        const int slot = h & 3;
        const size_t kby = (size_t)h * 64;
        #pragma unroll
        for (int rd = 0; rd < 2; ++rd)
            gload_lds16(Ag + (size_t)gar[rd] * Kb + kby + gac[rd],
                        lds + slot * ASL + rd * 8192 + w * 1024);
        #pragma unroll
        for (int rd = 0; rd < BRD; ++rd)
            gload_lds16(Bg + (size_t)gbr[rd] * Kb + kby + gbc[rd],
                        ldsB + slot * BSL + rd * 8192 + w * 1024);
    };

    // read-side swizzled offsets (2-way conflict-free)
    int offA[MF], offB[4];
    #pragma unroll
    for (int mi = 0; mi < MF; ++mi) {
        const int row = wr * MR + mi * 16 + l15;
        offA[mi] = (row & 127) * 128 + ((((row >> 7) * 64) + lg * 16) ^ ((l15 & 7) << 4));
    }
    #pragma unroll
    for (int nj = 0; nj < 4; ++nj) {
        const int row = wc * 64 + nj * 16 + l15;
        if (BN == 256)
            offB[nj] = (row & 127) * 128 + ((((row >> 7) * 64) + lg * 16) ^ ((l15 & 7) << 4));
        else
            offB[nj] = (row & 63) * 128 + ((((row >> 6) * 64) + lg * 16) ^ ((l15 & 7) << 4));
    }

    f32x4 acc[MF][4] = {};

    auto compute = [&](int hh) {
        const char* la = lds + (hh & 3) * ASL;
        const char* lb = ldsB + (hh & 3) * BSL;
        bf16x8 af[MF], bf[4];
        #pragma unroll
        for (int mi = 0; mi < MF; ++mi) af[mi] = *(const bf16x8*)(la + offA[mi]);
        #pragma unroll
        for (int nj = 0; nj < 4; ++nj) bf[nj] = *(const bf16x8*)(lb + offB[nj]);
        __builtin_amdgcn_s_setprio(1);
        #pragma unroll
        for (int mi = 0; mi < MF; ++mi)
            #pragma unroll
            for (int nj = 0; nj < 4; ++nj)
                acc[mi][nj] = __builtin_amdgcn_mfma_f32_16x16x32_bf16(af[mi], bf[nj], acc[mi][nj], 0, 0, 0);
        __builtin_amdgcn_s_setprio(0);
    };

    // prologue: 3 half-steps in flight, wait only for the first
    stage(0); stage(1); stage(2);
    waitvm<2 * LPS>();
    pipe_barrier();

    int h = 0;
    for (; h < H - 3; ++h) {
        compute(h);
        stage(h + 3);
        waitvm<2 * LPS>();   // retire half h+1 (own loads); barrier globalizes
        pipe_barrier();
    }
    compute(h); waitvm<LPS>(); pipe_barrier(); ++h;   // h = H-3: retire H-2
    compute(h); waitvm<0>();   pipe_barrier(); ++h;   // h = H-2: retire H-1
    compute(h);                                       // h = H-1

    // epilogue
    const int r00 = m0 + wr * MR + (lg << 2);
    const int c00 = n0 + wc * 64 + l15;
    #pragma unroll
    for (int nj = 0; nj < 4; ++nj) {
        const int c = c00 + nj * 16;
        if (MODE == 0) {
            const int which = c >> 10, hc = c & 1023;
            const int hh = hc >> 6, d = hc & 63;
            const float sc2 = (which == 0) ? 0.125f : 1.0f;
            u16* outp = outh + (size_t)which * ((size_t)NTOK * HID);
            #pragma unroll
            for (int mi = 0; mi < MF; ++mi)
                #pragma unroll
                for (int j = 0; j < 4; ++j) {
                    const int r = r00 + mi * 16 + j;
                    const int b = r >> 11, t = r & (SEQ - 1);
                    outp[((size_t)(b * NH + hh) * SEQ + t) * HD + d] = f2bf(acc[mi][nj][j] * sc2);
                }
        } else if (MODE == 1) {
            const float bi = bias[c];
            #pragma unroll
            for (int mi = 0; mi < MF; ++mi)
                #pragma unroll
                for (int j = 0; j < 4; ++j) {
                    const int r = r00 + mi * 16 + j;
                    const size_t idx = (size_t)r * N + c;
                    outf[idx] = resid[idx] + acc[mi][nj][j] + bi;
                }
        } else {
            const float bi = bias[c];
            #pragma unroll
            for (int mi = 0; mi < MF; ++mi)
                #pragma unroll
                for (int j = 0; j < 4; ++j) {
                    const int r = r00 + mi * 16 + j;
                    const float v = acc[mi][nj][j] + bi;
                    outh[(size_t)r * N + c] = f2bf(v > 0.f ? v : 0.f);
                }
        }
    }
}

// ---------------- Flash attention (causal), swapped-QK^T 32x32, in-reg softmax ----------------
__global__ __launch_bounds__(256) void attn_kernel(const u16* __restrict__ Q,
                                                   const u16* __restrict__ K,
                                                   const u16* __restrict__ Vt,
                                                   u16* __restrict__ O) {
    __shared__ u16 Kl[2][64 * 64];
    __shared__ u16 Vl[2][64 * 64];
    const int qt = (gridDim.x - 1) - blockIdx.x;   // heavy blocks first
    const int bh = blockIdx.y;
    const int tid = threadIdx.x, w = tid >> 6, l = tid & 63;
    const int q32 = l & 31, hi = l >> 5;
    const int qbase = qt * 128 + w * 32;
    const int qrow = qbase + q32;

    const u16* Qg = Q + ((size_t)bh * SEQ + qrow) * HD;
    bf16x8 qf[4];
    #pragma unroll
    for (int c = 0; c < 4; ++c)
        qf[c] = *(const bf16x8*)&Qg[c * 16 + hi * 8];

    f32x16 oa[2] = {};
    float m = -1e30f, lsum = 0.f;

    const u16* Kg0 = K + (size_t)bh * SEQ * HD;
    const u16* Vg0 = Vt + (size_t)bh * HD * SEQ;
    const int sr8 = tid >> 3;            // staging row 0..31 (+32 per round)
    const int sc8 = (tid & 7) * 16;      // staging col byte, 8 slots/row

    bf16x8 kreg[2], vreg[2];
    auto load_tile = [&](int st) {
        const char* Kg = (const char*)(Kg0 + (size_t)st * 64 * HD);
        const char* Vg = (const char*)(Vg0 + st * 64);
        #pragma unroll
        for (int it = 0; it < 2; it++) {
            kreg[it] = *(const bf16x8*)(Kg + (size_t)(it * 32 + sr8) * 128 + sc8);
            vreg[it] = *(const bf16x8*)(Vg + (size_t)(it * 32 + sr8) * (SEQ * 2) + sc8);
        }
    };
    auto write_tile = [&](int buf) {   // conflict-free: 8 rows x 8 swizzled slots per wave
        char* KlB = (char*)Kl[buf];
        char* VlB = (char*)Vl[buf];
        const int sw = (sr8 & 7) << 4;
        #pragma unroll
        for (int it = 0; it < 2; it++) {
            *(bf16x8*)(KlB + (it * 32 + sr8) * 128 + (sc8 ^ sw)) = kreg[it];
            *(bf16x8*)(VlB + (it * 32 + sr8) * 128 + (sc8 ^ sw)) = vreg[it];
        }
    };

    const int ntiles = 2 * qt + 2;
    const int tlast = (qbase + 31) >> 6;

    load_tile(0);
    write_tile(0);

    for (int st = 0; st < ntiles; ++st) {
        const int cur = st & 1;
        __syncthreads();
        const bool pf = (st + 1 < ntiles);
        if (pf) load_tile(st + 1);

        if (st <= tlast) {
            const char* KlB = (const char*)Kl[cur];
            const char* VlB = (const char*)Vl[cur];

            f32x16 s[2];
            __builtin_amdgcn_s_setprio(1);
            #pragma unroll
            for (int a = 0; a < 2; ++a) {
                const int row = a * 32 + q32;
                const char* base = KlB + row * 128;
                const int sw = (row & 7) << 4;
                f32x16 accs = {};
                #pragma unroll
                for (int ds4 = 0; ds4 < 4; ++ds4) {
                    bf16x8 kf = *(const bf16x8*)(base + ((ds4 * 32 + hi * 16) ^ sw));
                    accs = __builtin_amdgcn_mfma_f32_32x32x16_bf16(kf, qf[ds4], accs, 0, 0, 0);
                }
                s[a] = accs;
            }
            __builtin_amdgcn_s_setprio(0);

            if (st == tlast) {
                const int st64 = st * 64;
                #pragma unroll
                for (int a = 0; a < 2; ++a)
                    #pragma unroll
                    for (int r = 0; r < 16; ++r) {
                        const int kvg = st64 + a * 32 + (r & 3) + 8 * (r >> 2) + 4 * hi;
                        if (kvg > qrow) s[a][r] = -1e30f;
                    }
            }

            float pm0 = -1e30f, pm1 = -1e30f, pm2 = -1e30f, pm3 = -1e30f;
            #pragma unroll
            for (int r = 0; r < 16; r += 4) {
                pm0 = fmaxf(pm0, fmaxf(s[0][r + 0], s[1][r + 0]));
                pm1 = fmaxf(pm1, fmaxf(s[0][r + 1], s[1][r + 1]));
                pm2 = fmaxf(pm2, fmaxf(s[0][r + 2], s[1][r + 2]));
                pm3 = fmaxf(pm3, fmaxf(s[0][r + 3], s[1][r + 3]));
            }
            float pmax = fmaxf(fmaxf(pm0, pm1), fmaxf(pm2, pm3));
            pmax = fmaxf(pmax, __shfl_xor(pmax, 32, 64));

            if (!__all(pmax <= m + 8.f)) {
                const float newm = fmaxf(m, pmax);
                const float sc = __expf(m - newm);
                m = newm;
                lsum *= sc;
                #pragma unroll
                for (int d = 0; d < 2; ++d)
                    #pragma unroll
                    for (int r = 0; r < 16; ++r)
                        oa[d][r] *= sc;
            }

            float s0 = 0.f, s1 = 0.f, s2 = 0.f, s3 = 0.f;
            #pragma unroll
            for (int a = 0; a < 2; ++a)
                #pragma unroll
                for (int r = 0; r < 16; r += 4) {
                    float p0 = __expf(s[a][r + 0] - m);
                    float p1 = __expf(s[a][r + 1] - m);
                    float p2 = __expf(s[a][r + 2] - m);
                    float p3 = __expf(s[a][r + 3] - m);
                    s[a][r + 0] = p0; s[a][r + 1] = p1;
                    s[a][r + 2] = p2; s[a][r + 3] = p3;
                    s0 += p0; s1 += p1; s2 += p2; s3 += p3;
                }
            float psum = (s0 + s1) + (s2 + s3);
            psum += __shfl_xor(psum, 32, 64);
            lsum += psum;

            u32 W[2][4][2];
            #pragma unroll
            for (int a = 0; a < 2; ++a)
                #pragma unroll
                for (int i = 0; i < 4; ++i) {
                    W[a][i][0] = cvtpk(s[a][4 * i + 0], s[a][4 * i + 1]);
                    W[a][i][1] = cvtpk(s[a][4 * i + 2], s[a][4 * i + 3]);
                }
            bf16x8 pa[4];
            #pragma unroll
            for (int a = 0; a < 2; ++a)
                #pragma unroll
                for (int j = 0; j < 2; ++j) {
                    u32 a0 = W[a][2 * j][0], b0 = W[a][2 * j + 1][0];
                    u32 a1 = W[a][2 * j][1], b1 = W[a][2 * j + 1][1];
                    plswap(a0, b0);
                    plswap(a1, b1);
                    union { u32 ww[4]; bf16x8 v; } u_;
                    u_.ww[0] = a0; u_.ww[1] = a1; u_.ww[2] = b0; u_.ww[3] = b1;
                    pa[2 * a + j] = u_.v;
                }

            __builtin_amdgcn_s_setprio(1);
            #pragma unroll
            for (int dblk = 0; dblk < 2; ++dblk) {
                const int row = dblk * 32 + q32;
                const char* base = VlB + row * 128;
                const int sw = (row & 7) << 4;
                #pragma unroll
                for (int s4 = 0; s4 < 4; ++s4) {
                    bf16x8 vf = *(const bf16x8*)(base + ((s4 * 32 + hi * 16) ^ sw));
                    oa[dblk] = __builtin_amdgcn_mfma_f32_32x32x16_bf16(vf, pa[s4], oa[dblk], 0, 0, 0);
                }
            }
            __builtin_amdgcn_s_setprio(0);
        }

        if (pf) write_tile(cur ^ 1);
    }

    const int b = bh >> 4, h = bh & 15;
    const float inv = 1.f / lsum;
    u16* Orow = O + ((size_t)b * SEQ + qrow) * HID + h * HD;
    #pragma unroll
    for (int dblk = 0; dblk < 2; ++dblk)
        #pragma unroll
        for (int i = 0; i < 4; ++i) {
            ushort4 st4;
            st4.x = f2bf(oa[dblk][4 * i + 0] * inv);
            st4.y = f2bf(oa[dblk][4 * i + 1] * inv);
            st4.z = f2bf(oa[dblk][4 * i + 2] * inv);
            st4.w = f2bf(oa[dblk][4 * i + 3] * inv);
            *(ushort4*)&Orow[dblk * 32 + 8 * i + 4 * hi] = st4;
        }
}

// ---------------- launch ----------------
extern "C" void kernel_launch(void* const* d_in, const int* in_sizes, int n_in,
                              void* d_out, int out_size, void* d_ws, size_t ws_size,
                              hipStream_t stream) {
    (void)in_sizes; (void)n_in; (void)out_size; (void)ws_size;
    const float* x   = (const float*)d_in[0];
    const float* Wq  = (const float*)d_in[1];
    const float* Wk  = (const float*)d_in[2];
    const float* Wv  = (const float*)d_in[3];
    const float* Wo  = (const float*)d_in[4];
    const float* bo  = (const float*)d_in[5];
    const float* W1  = (const float*)d_in[6];
    const float* b1  = (const float*)d_in[7];
    const float* W2  = (const float*)d_in[8];
    const float* b2  = (const float*)d_in[9];
    const float* g1  = (const float*)d_in[10];
    const float* be1 = (const float*)d_in[11];
    const float* g2  = (const float*)d_in[12];
    const float* be2 = (const float*)d_in[13];
    float* out = (float*)d_out;

    char* ws = (char*)d_ws;
    size_t off = 0;
    auto alloc = [&](size_t bytes) { void* p = ws + off; off += bytes; return p; };
    u16* Wqkv_t = (u16*)alloc((size_t)3 * HID * HID * 2);
    u16* Wo_t = (u16*)alloc((size_t)HID * HID * 2);
    u16* W1_t = (u16*)alloc((size_t)DFF * HID * 2);
    u16* W2_t = (u16*)alloc((size_t)HID * DFF * 2);
    u16* h1   = (u16*)alloc((size_t)NTOK * HID * 2);   // reused as h2
    u16* Qb   = (u16*)alloc((size_t)NTOK * HID * 2);
    u16* Kb   = (u16*)alloc((size_t)NTOK * HID * 2);
    u16* Vb   = (u16*)alloc((size_t)NTOK * HID * 2);   // reused as attn_out
    u16* Vt   = (u16*)alloc((size_t)NTOK * HID * 2);
    float* x2 = (float*)alloc((size_t)NTOK * HID * 4);
    u16* ff1  = Qb;

    transpose_w<<<dim3(32, 2, 16), 256, 0, stream>>>(Wq, Wqkv_t, HID, HD);
    transpose_w<<<dim3(32, 2, 16), 256, 0, stream>>>(Wk, Wqkv_t + (size_t)HID * HID, HID, HD);
    transpose_w<<<dim3(32, 2, 16), 256, 0, stream>>>(Wv, Wqkv_t + (size_t)2 * HID * HID, HID, HD);
    transpose_w<<<dim3(32, 32, 1), 256, 0, stream>>>(Wo, Wo_t, HID, HID);
    transpose_w<<<dim3(32, 128, 1), 256, 0, stream>>>(W1, W1_t, HID, DFF);
    transpose_w<<<dim3(128, 32, 1), 256, 0, stream>>>(W2, W2_t, DFF, HID);

    ln_kernel<<<NTOK, 256, 0, stream>>>(x, g1, be1, h1);

    // merged QKV: [8192 x 3072], grid 32x24 = 768 blocks (3 full CU rounds)
    gemm_p<128, 0><<<dim3(32 * 24), 512, 0, stream>>>(h1, Wqkv_t, nullptr, Qb,
                                                      nullptr, nullptr, HID, 3072);

    transpose_v<<<dim3(SEQ / 64, BATCH * NH), 256, 0, stream>>>(Vb, Vt);

    u16* attn_out = Vb;
    attn_kernel<<<dim3(SEQ / 128, BATCH * NH), 256, 0, stream>>>(Qb, Kb, Vt, attn_out);

    // x2 = x + attn_out @ Wo + bo : grid 32x8 = 256 (1 full round)
    gemm_p<128, 1><<<dim3(32 * 8), 512, 0, stream>>>(attn_out, Wo_t, x2, nullptr, bo, x, HID, HID);

    ln_kernel<<<NTOK, 256, 0, stream>>>(x2, g2, be2, h1);

    // ff1 = relu(h2 @ W1 + b1): [8192 x 4096], grid 32x16 = 512 (2 full rounds)
    gemm_p<256, 2><<<dim3(32 * 16), 512, 0, stream>>>(h1, W1_t, nullptr, ff1, b1, nullptr, HID, DFF);

    // out = x2 + ff1 @ W2 + b2: K=4096, grid 256 (1 full round)
    gemm_p<128, 1><<<dim3(32 * 8), 512, 0, stream>>>(ff1, W2_t, out, nullptr, b2, x2, DFF, HID);
}